// Round 1
// 1762.850 us; speedup vs baseline: 1.8904x; 1.8904x over previous
//
#include <hip/hip_runtime.h>

// LSTM_8650064134553 : 2-layer stacked LSTM, B=32768, D=128, H=64, 32 steps.
// Round 2: move all three GEMMs to bf16 MFMA (16x16x32) with hi/lo split
// (3-term Ootomo) for fp32-grade accuracy. Gate columns permuted at pack
// time so i/f/g/o for a cell land in the same lane. Activations staged in
// LDS as bf16 hi/lo planes with XOR bank swizzle; cell state in registers.

#define B_      32768
#define D_      128
#define H_      64
#define NSTEP_  32
#define ROWS_   64
#define NTHR_   256
#define NBLK_   (B_ / ROWS_)   // 512 blocks -> 2 blocks/CU

typedef __attribute__((ext_vector_type(8))) short  short8v;  // 8 bf16
typedef __attribute__((ext_vector_type(4))) float  float4v;  // mfma acc

// packed-weight offsets in ushort units inside d_ws (total 360448 B)
#define B0H_OFF 0           // 16 ntile * 6 ktile * 64 lane * 8 = 49152
#define B0L_OFF 49152
#define B1H_OFF 98304       // 16 * 4 * 64 * 8 = 32768
#define B1L_OFF 131072
#define BFH_OFF 163840      // 8 * 2 * 64 * 8 = 8192
#define BFL_OFF 172032

// byte offset into an act plane: row-major [64][256] bf16 (512 B rows),
// XOR-swizzled so stride-512 ds_read_b128 columns spread across banks.
#define SWZ(row, bytecol) ((row) * 512 + ((bytecol) ^ (((row) & 7) << 4)))

__device__ __forceinline__ ushort f2bf(float f) {
  uint u = __float_as_uint(f);
  u += 0x7fffu + ((u >> 16) & 1u);      // RNE
  return (ushort)(u >> 16);
}
__device__ __forceinline__ float bf2f(ushort h) {
  return __uint_as_float((uint)h << 16);
}
__device__ __forceinline__ float fsig(float x) {
  float e = __builtin_amdgcn_exp2f(-1.44269504088896f * x);
  return __builtin_amdgcn_rcpf(1.0f + e);
}
__device__ __forceinline__ float ftanh(float x) {
  float e = __builtin_amdgcn_exp2f(2.88539008177793f * x);
  return 1.0f - 2.0f * __builtin_amdgcn_rcpf(e + 1.0f);
}

// Pack weights into MFMA B-fragment order, split into bf16 hi/lo.
// B-fragment (16x16x32): lane l supplies B[k][n] with n = l&15,
// k = (l>>4)*8 + e, e = 0..7 (8 contiguous k per lane).
// N-tile permutation: tile n -> gate q = n&3, cell group g = n>>2,
// original output column = q*64 + g*16 + (l&15).
__global__ void prep_w(const float* __restrict__ Wih0,
                       const float* __restrict__ Whh0,
                       const float* __restrict__ Wih1,
                       const float* __restrict__ Whh1,
                       const float* __restrict__ Wfc,
                       ushort* __restrict__ ws) {
  int idx = blockIdx.x * blockDim.x + threadIdx.x;
  int np  = gridDim.x * blockDim.x;
  // layer 0: K = 192 = [y(128) | h0(64)], 16 N-tiles x 6 k-tiles
  for (int i = idx; i < 16 * 6 * 64 * 8; i += np) {
    int e = i & 7, l = (i >> 3) & 63, r = i >> 9;
    int kt = r % 6, n = r / 6;
    int col = (n & 3) * 64 + (n >> 2) * 16 + (l & 15);
    int k   = kt * 32 + (l >> 4) * 8 + e;
    float v = (k < D_) ? Wih0[col * D_ + k] : Whh0[col * H_ + (k - D_)];
    ushort hi = f2bf(v);
    ws[B0H_OFF + i] = hi;
    ws[B0L_OFF + i] = f2bf(v - bf2f(hi));
  }
  // layer 1: K = 128 = [h0(64) | h1(64)], 16 N-tiles x 4 k-tiles
  for (int i = idx; i < 16 * 4 * 64 * 8; i += np) {
    int e = i & 7, l = (i >> 3) & 63, r = i >> 9;
    int kt = r & 3, n = r >> 2;
    int col = (n & 3) * 64 + (n >> 2) * 16 + (l & 15);
    int k   = kt * 32 + (l >> 4) * 8 + e;
    float v = (k < H_) ? Wih1[col * H_ + k] : Whh1[col * H_ + (k - H_)];
    ushort hi = f2bf(v);
    ws[B1H_OFF + i] = hi;
    ws[B1L_OFF + i] = f2bf(v - bf2f(hi));
  }
  // fc: K = 64 = h1, 8 N-tiles (natural order) x 2 k-tiles
  for (int i = idx; i < 8 * 2 * 64 * 8; i += np) {
    int e = i & 7, l = (i >> 3) & 63, r = i >> 9;
    int kt = r & 1, n = r >> 1;
    int col = n * 16 + (l & 15);
    int k   = kt * 32 + (l >> 4) * 8 + e;
    float v = Wfc[col * H_ + k];
    ushort hi = f2bf(v);
    ws[BFH_OFF + i] = hi;
    ws[BFL_OFF + i] = f2bf(v - bf2f(hi));
  }
}

__global__ __launch_bounds__(NTHR_, 2)
void lstm_fused(const float* __restrict__ x,
                const float* __restrict__ b0,
                const float* __restrict__ b1,
                const float* __restrict__ bfc,
                const ushort* __restrict__ ws,
                float* __restrict__ out) {
  // act layout per row (256 bf16 cols): [ y(0..127) | h0(128..191) | h1(192..255) ]
  __shared__ __align__(16) ushort act_h[ROWS_ * 256];   // 32 KB
  __shared__ __align__(16) ushort act_l[ROWS_ * 256];   // 32 KB

  const int tid  = threadIdx.x;
  const int l    = tid & 63;
  const int cg   = tid >> 6;       // wave id = cell group (16 cells)
  const int c16  = l & 15;
  const int lq   = l >> 4;
  const int row0 = blockIdx.x * ROWS_;

  const short8v* B0h = (const short8v*)(ws + B0H_OFF);
  const short8v* B0l = (const short8v*)(ws + B0L_OFF);
  const short8v* B1h = (const short8v*)(ws + B1H_OFF);
  const short8v* B1l = (const short8v*)(ws + B1L_OFF);
  const short8v* Bfh = (const short8v*)(ws + BFH_OFF);
  const short8v* Bfl = (const short8v*)(ws + BFL_OFF);

  const int ucol = cg * 16 + c16;  // this lane's cell unit 0..63
  const float bi0 = b0[ucol], bf0 = b0[64 + ucol], bg0 = b0[128 + ucol], bo0 = b0[192 + ucol];
  const float bi1 = b1[ucol], bf1 = b1[64 + ucol], bg1 = b1[128 + ucol], bo1 = b1[192 + ucol];
  const float by0 = bfc[cg * 32 + c16], by1 = bfc[cg * 32 + 16 + c16];

  float c0s[16], c1s[16];
#pragma unroll
  for (int i = 0; i < 16; ++i) { c0s[i] = 0.f; c1s[i] = 0.f; }

  // init: x -> act cols 0..127 (hi/lo), zero h0/h1 cols
  for (int i = tid; i < ROWS_ * D_; i += NTHR_) {
    int row = i >> 7, col = i & 127;
    float v = x[(size_t)(row0 + row) * D_ + col];
    ushort hh = f2bf(v);
    ushort hl = f2bf(v - bf2f(hh));
    int off = SWZ(row, col * 2);
    *(ushort*)((char*)act_h + off) = hh;
    *(ushort*)((char*)act_l + off) = hl;
  }
  for (int i = tid; i < ROWS_ * 128; i += NTHR_) {
    int row = i >> 7, col = 128 + (i & 127);
    int off = SWZ(row, col * 2);
    *(ushort*)((char*)act_h + off) = 0;
    *(ushort*)((char*)act_l + off) = 0;
  }
  __syncthreads();

  const float4v zf = {0.f, 0.f, 0.f, 0.f};

  for (int t = 0; t < NSTEP_; ++t) {
    // ================= layer 0 : gates = [y | h0] @ W0 =================
    float4v acc[4][4];
#pragma unroll
    for (int q = 0; q < 4; ++q)
#pragma unroll
      for (int mt = 0; mt < 4; ++mt) acc[q][mt] = zf;

#pragma unroll
    for (int kt = 0; kt < 6; ++kt) {
      short8v ah[4], al[4];
#pragma unroll
      for (int mt = 0; mt < 4; ++mt) {
        int row = mt * 16 + c16;
        int off = SWZ(row, (kt * 32 + lq * 8) * 2);
        ah[mt] = *(const short8v*)((char*)act_h + off);
        al[mt] = *(const short8v*)((char*)act_l + off);
      }
      short8v bh[4], bl[4];
#pragma unroll
      for (int q = 0; q < 4; ++q) {
        int idx = ((cg * 4 + q) * 6 + kt) * 64 + l;
        bh[q] = B0h[idx];
        bl[q] = B0l[idx];
      }
#pragma unroll
      for (int q = 0; q < 4; ++q)
#pragma unroll
        for (int mt = 0; mt < 4; ++mt) {
          acc[q][mt] = __builtin_amdgcn_mfma_f32_16x16x32_bf16(ah[mt], bh[q], acc[q][mt], 0, 0, 0);
          acc[q][mt] = __builtin_amdgcn_mfma_f32_16x16x32_bf16(al[mt], bh[q], acc[q][mt], 0, 0, 0);
          acc[q][mt] = __builtin_amdgcn_mfma_f32_16x16x32_bf16(ah[mt], bl[q], acc[q][mt], 0, 0, 0);
        }
    }
    __syncthreads();   // all waves done reading old h0 region

#pragma unroll
    for (int mt = 0; mt < 4; ++mt)
#pragma unroll
      for (int j = 0; j < 4; ++j) {
        float ig = fsig (acc[0][mt][j] + bi0);
        float fg = fsig (acc[1][mt][j] + bf0);
        float gg = ftanh(acc[2][mt][j] + bg0);
        float og = fsig (acc[3][mt][j] + bo0);
        float cn = fmaf(fg, c0s[mt * 4 + j], ig * gg);
        c0s[mt * 4 + j] = cn;
        float h = og * ftanh(cn);
        ushort hh = f2bf(h);
        ushort hl = f2bf(h - bf2f(hh));
        int row = mt * 16 + lq * 4 + j;
        int off = SWZ(row, (128 + ucol) * 2);
        *(ushort*)((char*)act_h + off) = hh;
        *(ushort*)((char*)act_l + off) = hl;
      }
    __syncthreads();   // new h0 visible

    // ================= layer 1 : gates = [h0 | h1] @ W1 =================
#pragma unroll
    for (int q = 0; q < 4; ++q)
#pragma unroll
      for (int mt = 0; mt < 4; ++mt) acc[q][mt] = zf;

#pragma unroll
    for (int kt = 0; kt < 4; ++kt) {
      short8v ah[4], al[4];
#pragma unroll
      for (int mt = 0; mt < 4; ++mt) {
        int row = mt * 16 + c16;
        int off = SWZ(row, (128 + kt * 32 + lq * 8) * 2);
        ah[mt] = *(const short8v*)((char*)act_h + off);
        al[mt] = *(const short8v*)((char*)act_l + off);
      }
      short8v bh[4], bl[4];
#pragma unroll
      for (int q = 0; q < 4; ++q) {
        int idx = ((cg * 4 + q) * 4 + kt) * 64 + l;
        bh[q] = B1h[idx];
        bl[q] = B1l[idx];
      }
#pragma unroll
      for (int q = 0; q < 4; ++q)
#pragma unroll
        for (int mt = 0; mt < 4; ++mt) {
          acc[q][mt] = __builtin_amdgcn_mfma_f32_16x16x32_bf16(ah[mt], bh[q], acc[q][mt], 0, 0, 0);
          acc[q][mt] = __builtin_amdgcn_mfma_f32_16x16x32_bf16(al[mt], bh[q], acc[q][mt], 0, 0, 0);
          acc[q][mt] = __builtin_amdgcn_mfma_f32_16x16x32_bf16(ah[mt], bl[q], acc[q][mt], 0, 0, 0);
        }
    }
    __syncthreads();   // all waves done reading old h1 region

#pragma unroll
    for (int mt = 0; mt < 4; ++mt)
#pragma unroll
      for (int j = 0; j < 4; ++j) {
        float ig = fsig (acc[0][mt][j] + bi1);
        float fg = fsig (acc[1][mt][j] + bf1);
        float gg = ftanh(acc[2][mt][j] + bg1);
        float og = fsig (acc[3][mt][j] + bo1);
        float cn = fmaf(fg, c1s[mt * 4 + j], ig * gg);
        c1s[mt * 4 + j] = cn;
        float h = og * ftanh(cn);
        ushort hh = f2bf(h);
        ushort hl = f2bf(h - bf2f(hh));
        int row = mt * 16 + lq * 4 + j;
        int off = SWZ(row, (192 + ucol) * 2);
        *(ushort*)((char*)act_h + off) = hh;
        *(ushort*)((char*)act_l + off) = hl;
      }
    __syncthreads();   // new h1 visible

    // ================= fc : y = h1 @ Wfc^T + bfc =================
    float4v af[2][4];
#pragma unroll
    for (int nq = 0; nq < 2; ++nq)
#pragma unroll
      for (int mt = 0; mt < 4; ++mt) af[nq][mt] = zf;

#pragma unroll
    for (int kt = 0; kt < 2; ++kt) {
      short8v ah[4], al[4];
#pragma unroll
      for (int mt = 0; mt < 4; ++mt) {
        int row = mt * 16 + c16;
        int off = SWZ(row, (192 + kt * 32 + lq * 8) * 2);
        ah[mt] = *(const short8v*)((char*)act_h + off);
        al[mt] = *(const short8v*)((char*)act_l + off);
      }
      short8v bh2[2], bl2[2];
#pragma unroll
      for (int nq = 0; nq < 2; ++nq) {
        int idx = ((cg * 2 + nq) * 2 + kt) * 64 + l;
        bh2[nq] = Bfh[idx];
        bl2[nq] = Bfl[idx];
      }
#pragma unroll
      for (int nq = 0; nq < 2; ++nq)
#pragma unroll
        for (int mt = 0; mt < 4; ++mt) {
          af[nq][mt] = __builtin_amdgcn_mfma_f32_16x16x32_bf16(ah[mt], bh2[nq], af[nq][mt], 0, 0, 0);
          af[nq][mt] = __builtin_amdgcn_mfma_f32_16x16x32_bf16(al[mt], bh2[nq], af[nq][mt], 0, 0, 0);
          af[nq][mt] = __builtin_amdgcn_mfma_f32_16x16x32_bf16(ah[mt], bl2[nq], af[nq][mt], 0, 0, 0);
        }
    }

    // epilogue: write y to global out and feed back into act cols 0..127.
    // (writes touch cols 0..127 only; concurrent fc reads are cols 192..255)
    const size_t obase = (size_t)(t + 1) * (B_ * D_) + (size_t)row0 * D_;
    const int coly0 = cg * 32 + c16;
    const int coly1 = coly0 + 16;
#pragma unroll
    for (int mt = 0; mt < 4; ++mt)
#pragma unroll
      for (int j = 0; j < 4; ++j) {
        int row = mt * 16 + lq * 4 + j;
        float y0v = af[0][mt][j] + by0;
        float y1v = af[1][mt][j] + by1;
        out[obase + (size_t)row * D_ + coly0] = y0v;
        out[obase + (size_t)row * D_ + coly1] = y1v;
        if (t == NSTEP_ - 1) {
          out[(size_t)(row0 + row) * D_ + coly0] = y0v;
          out[(size_t)(row0 + row) * D_ + coly1] = y1v;
        }
        ushort h0h = f2bf(y0v);
        ushort h0l = f2bf(y0v - bf2f(h0h));
        ushort h1h = f2bf(y1v);
        ushort h1l = f2bf(y1v - bf2f(h1h));
        int off0 = SWZ(row, coly0 * 2);
        int off1 = SWZ(row, coly1 * 2);
        *(ushort*)((char*)act_h + off0) = h0h;
        *(ushort*)((char*)act_l + off0) = h0l;
        *(ushort*)((char*)act_h + off1) = h1h;
        *(ushort*)((char*)act_l + off1) = h1l;
      }
    __syncthreads();   // y/h ready for next step's layer-0 GEMM
  }
}

extern "C" void kernel_launch(void* const* d_in, const int* in_sizes, int n_in,
                              void* d_out, int out_size, void* d_ws, size_t ws_size,
                              hipStream_t stream) {
  const float* x    = (const float*)d_in[0];
  const float* Wih0 = (const float*)d_in[1];
  const float* Whh0 = (const float*)d_in[2];
  const float* b0   = (const float*)d_in[3];
  const float* Wih1 = (const float*)d_in[4];
  const float* Whh1 = (const float*)d_in[5];
  const float* b1   = (const float*)d_in[6];
  const float* Wfc  = (const float*)d_in[7];
  const float* bfc  = (const float*)d_in[8];
  ushort* ws  = (ushort*)d_ws;
  float* out  = (float*)d_out;

  prep_w<<<64, NTHR_, 0, stream>>>(Wih0, Whh0, Wih1, Whh1, Wfc, ws);
  lstm_fused<<<NBLK_, NTHR_, 0, stream>>>(x, b0, b1, bfc, ws, out);
}